// Round 3
// baseline (261.547 us; speedup 1.0000x reference)
//
#include <hip/hip_runtime.h>
#include <stddef.h>

// Correlation cost volume via bf16 MFMA band-matmul.
// out[b, di*9+dj, h, w] = (1/256) * sum_c x1[b,c,h,w] * x2[b,c,h+di-4,w+dj-4]
// B=4, C=256, H=96, W=192.
//
// R5 -> R6: R5 was VALU+latency-bound in the inner loop: per-chunk f2bf
// conversion of the 4.5x-redundant x2 tile (32 f2bf/thread/chunk) + float4
// staging = 43k VALU cy/SIMD (biggest busy pipe at 21%), with 1.9e7 LDS
// bank-conflict cycles from the ushort2 scatter writes. Fix: transpose+cast
// BOTH inputs ONCE in a pre-pass into workspace as xt[b][h][w][c] bf16
// (channel-fastest). Main kernel then:
//  - A-frag = one 16B global load (no conversion, no strided gather)
//  - x2 staging = 16B loads + ds_write_b128 (no f2bf in loop)
//  - LDS tile [row][w][32ch], w-stride 36 ushorts -> uniform-bank b128
//    reads/writes (8 dwords/bank = minimum)
//  - double-buffered LDS, ONE barrier per chunk; OOB halo zero-filled once
// Falls back to the R5 kernel if ws_size < 75.5 MB.

#define NB 4
#define NC 256
#define HH 96
#define WW 192
#define TW 16
#define TH 4
#define KC 32
#define NROWS 12   // TH + 8 halo rows
#define CHW (HH * WW)
#define KSTRIDE (KC * CHW)
#define NTASK 1152            // 12 rows x 24 w x 4 subgroups (16B each)

#define XT_ELEMS (NB * HH * WW * NC)          // 18,874,368 per tensor
#define XT_BYTES ((size_t)XT_ELEMS * 2)       // 37,748,736 B

// Main-kernel LDS tile: [row][w][32ch] bf16, w-stride 36 ushorts (32 + 4 pad
// -> 18-dword stride spreads b128 banks uniformly), row-stride 24*36 = 864.
#define WSTR 36
#define RSTR (24 * WSTR)      // 864
#define BUFSZ 10688           // >= 11*864 + 31*36 + 24 + 8 = 10652, 32-aligned

typedef __attribute__((ext_vector_type(8))) short bf16x8;
typedef __attribute__((ext_vector_type(4))) float f32x4;

__device__ __forceinline__ unsigned short f2bf(float f) {
    union { float f; unsigned u; } c; c.f = f;
    unsigned r = c.u + 0x7FFFu + ((c.u >> 16) & 1u);   // round-to-nearest-even
    return (unsigned short)(r >> 16);
}

// ---------------- pre-pass: x[b][c][h][w] f32 -> xt[b][h][w][c] bf16 -------
__global__ __launch_bounds__(256) void transpose_cast(
    const float* __restrict__ x1, const float* __restrict__ x2,
    unsigned short* __restrict__ xt1, unsigned short* __restrict__ xt2)
{
    __shared__ float t[64][65];
    int lin = blockIdx.x;
    const int wt = lin % 3; lin /= 3;
    const int ct = lin & 3; lin >>= 2;
    const int h  = lin % 96; lin /= 96;
    const int b  = lin & 3;  lin >>= 2;          // lin now = tensor select
    const float* __restrict__ src = lin ? x2 : x1;
    unsigned short* __restrict__ dst = lin ? xt2 : xt1;
    const int w0 = wt * 64, c0 = ct * 64;

    const int wi = threadIdx.x & 63, c4 = threadIdx.x >> 6;
#pragma unroll
    for (int it = 0; it < 16; ++it) {
        const int c = it * 4 + c4;
        t[c][wi] = src[((size_t)((b * NC + c0 + c) * HH + h)) * WW + w0 + wi];
    }
    __syncthreads();
    const int co = (threadIdx.x & 31) * 2, wo = threadIdx.x >> 5;
#pragma unroll
    for (int it = 0; it < 8; ++it) {
        const int w = it * 8 + wo;
        ushort2 v;
        v.x = f2bf(t[co][w]);
        v.y = f2bf(t[co + 1][w]);
        *(ushort2*)&dst[((size_t)((b * HH + h) * WW + w0 + w)) * NC + c0 + co] = v;
    }
}

// ---------------- main: band-matmul from bf16 transposed inputs ------------
__global__ __launch_bounds__(512, 4) void corr_mfma_bt(
    const unsigned short* __restrict__ xt1,
    const unsigned short* __restrict__ xt2,
    float* __restrict__ out)
{
    __shared__ union {
        unsigned short xb[2 * BUFSZ];      // 42,752 B: double-buffered x2 tile
        float band[TH][9][9][18];          // 23,328 B: epilogue staging
    } lds;

    // XCD-aware swizzle: 1152 blocks, 144 consecutive tiles per XCD.
    const int lin = blockIdx.x;
    const int sw  = (lin & 7) * 144 + (lin >> 3);
    const int b   = sw / 288;
    const int t2  = sw - b * 288;
    const int ty  = t2 / 12;
    const int tx  = t2 - ty * 12;

    const int tid  = threadIdx.x;
    const int wv   = tid >> 6;
    const int lane = tid & 63;
    const int col  = lane & 15;       // MFMA m/n 16-index
    const int q    = lane >> 4;       // MFMA k-quad
    const int r    = wv & 3;          // output row within tile
    const int dig  = wv >> 2;         // unit group: 0 -> units 0..8, 1 -> 9..17
    const int w0   = tx * TW;
    const int h0   = ty * TH;
    const int h    = h0 + r;

    f32x4 acc[9];
#pragma unroll
    for (int s = 0; s < 9; ++s) acc[s] = (f32x4)0.0f;

    // ---- staging task decode: 1152 16B-groups/chunk, <=3/thread.
    // g = row*96 + w*4 + sub: consecutive g = consecutive 16B in global.
    unsigned go2[3];
    int      lof[3];
    bool     okk[3];
#pragma unroll
    for (int k = 0; k < 3; ++k) {
        const int g   = tid + k * 512;
        const bool act = (g < NTASK);
        const int row = g / 96;
        const int rem = g - row * 96;
        const int w   = rem >> 2;
        const int sub = rem & 3;
        const int gh  = h0 - 4 + row;
        const int gw  = w0 - 4 + w;
        const bool inb = (gh >= 0) & (gh < HH) & (gw >= 0) & (gw < WW);
        okk[k] = act & inb;
        const int ghc = gh < 0 ? 0 : (gh > HH - 1 ? HH - 1 : gh);
        const int gwc = gw < 0 ? 0 : (gw > WW - 1 ? WW - 1 : gw);
        const int rwc = row > NROWS - 1 ? NROWS - 1 : row;
        go2[k] = (unsigned)(((b * HH + ghc) * WW + gwc) * NC + sub * 8);
        lof[k] = rwc * RSTR + w * WSTR + sub * 8;
        // OOB halo slots: zero once, in BOTH buffers (chunk-invariant).
        if (act & !inb) {
            uint4 z = make_uint4(0, 0, 0, 0);
            *(uint4*)&lds.xb[lof[k]] = z;
            *(uint4*)&lds.xb[BUFSZ + lof[k]] = z;
        }
    }

    // ---- preload chunk 0 (x2 groups + x1 A-frag)
    uint4 pfu[3];
#pragma unroll
    for (int k = 0; k < 3; ++k) {
        if (okk[k]) pfu[k] = *(const uint4*)&xt2[go2[k]];
        go2[k] += KC;
    }
    unsigned o1 = (unsigned)(((b * HH + h) * WW + w0 + col) * NC + q * 8);
    bf16x8 a_cur = *(const bf16x8*)&xt1[o1]; o1 += KC;
    bf16x8 a_nxt = a_cur;

    const int rb = r * RSTR + q * 8;

#pragma unroll
    for (int ci = 0; ci < 8; ++ci) {
        const int pb = (ci & 1) * BUFSZ;
        // write chunk ci's staged regs into buf[ci&1]
#pragma unroll
        for (int k = 0; k < 3; ++k)
            if (okk[k]) *(uint4*)&lds.xb[pb + lof[k]] = pfu[k];
        // issue chunk ci+1's loads; they fly across the barrier + MFMA phase
        if (ci < 7) {
#pragma unroll
            for (int k = 0; k < 3; ++k) {
                if (okk[k]) pfu[k] = *(const uint4*)&xt2[go2[k]];
                go2[k] += KC;
            }
            a_nxt = *(const bf16x8*)&xt1[o1]; o1 += KC;
        }
        __syncthreads();   // buf[ci&1] complete; prior reads of buf[ci&1] (chunk ci-2) long done
        // this wave's 9 (di, half) units from buf[ci&1]
#pragma unroll
        for (int s = 0; s < 9; ++s) {
            const int u  = dig * 9 + s;
            const int di = u >> 1;
            const int n  = (u & 1) * 16 + col;
            const bf16x8 bb = *(const bf16x8*)&lds.xb[pb + rb + di * RSTR + n * WSTR];
            acc[s] = __builtin_amdgcn_mfma_f32_16x16x32_bf16(a_cur, bb, acc[s], 0, 0, 0);
        }
        a_cur = a_nxt;
    }
    __syncthreads();   // all frag reads done before band overwrites the union

    // ---- band extraction: P[m, m+dj] -> band[r][di][dj][m]
#pragma unroll
    for (int s = 0; s < 9; ++s) {
        const int u  = dig * 9 + s;
        const int di = u >> 1;
        const int uh = u & 1;
#pragma unroll
        for (int rg = 0; rg < 4; ++rg) {
            int m  = q * 4 + rg;
            int dj = uh * 16 + col - m;
            if (dj >= 0 && dj < 9)
                lds.band[r][di][dj][m] = acc[s][rg];
        }
    }
    __syncthreads();

    // ---- coalesced write-out: 81 channels x 4 rows x 16 w per block
    const float scale = 1.0f / 256.0f;
#pragma unroll
    for (int it = 0; it < 11; ++it) {
        int gi = it * 32 + (tid >> 4);    // gi = combo*4 + row, 324 total
        if (gi < 324) {
            int combo = gi >> 2;
            int row   = gi & 3;
            float v = lds.band[row][combo / 9][combo % 9][tid & 15];
            out[((size_t)((b * 81 + combo) * HH + h0 + row)) * WW + w0 + (tid & 15)] = v * scale;
        }
    }
}

// ---------------- fallback (R5 kernel, used when ws_size is too small) -----
#define KS 264
#define RS 1096
#define XBI(row, kg, n) ((row) * RS + (kg) * KS + (n) * 8)

__global__ __launch_bounds__(512, 4) void corr_mfma_fb(
    const float* __restrict__ x1, const float* __restrict__ x2,
    float* __restrict__ out)
{
    __shared__ union {
        unsigned short xb[NROWS * RS];
        float band[TH][9][9][18];
    } lds;

    const int lin = blockIdx.x;
    const int sw  = (lin & 7) * 144 + (lin >> 3);
    const int b   = sw / 288;
    const int t2  = sw - b * 288;
    const int ty  = t2 / 12;
    const int tx  = t2 - ty * 12;

    const int tid  = threadIdx.x;
    const int wv   = tid >> 6;
    const int lane = tid & 63;
    const int col  = lane & 15;
    const int q    = lane >> 4;
    const int r    = wv & 3;
    const int dig  = wv >> 2;
    const int w0   = tx * TW;
    const int h0   = ty * TH;
    const int h    = h0 + r;

    f32x4 acc[9];
#pragma unroll
    for (int s = 0; s < 9; ++s) acc[s] = (f32x4)0.0f;

    unsigned o2k[3];
    int      lofk[3];
    bool     okk[3];
    bool     act[3];
#pragma unroll
    for (int k = 0; k < 3; ++k) {
        const int t   = tid + k * 512;
        act[k] = (t < NTASK);
        const int seg = t % 6;
        const int u   = t / 6;
        const int cp  = u & 15;
        const int row = u >> 4;
        const int gh  = h0 - 4 + row;
        const int gw  = w0 - 4 + seg * 4;
        okk[k] = act[k] & (gh >= 0) & (gh < HH) & (gw >= 0) & (gw <= WW - 4);
        const int ghc = gh < 0 ? 0 : (gh > HH - 1 ? HH - 1 : gh);
        const int gwc = gw < 0 ? 0 : gw;
        const int rwc = row > NROWS - 1 ? NROWS - 1 : row;
        o2k[k]  = (unsigned)(((b * NC + cp * 2) * HH + ghc) * WW + gwc);
        lofk[k] = XBI(rwc, cp >> 2, seg * 4) + (cp & 3) * 2;
    }
    unsigned o1 = (unsigned)(((b * NC + q * 8) * HH + h) * WW + w0 + col);

    float pf[24];
    float pa[8];

#define STAGE_LOAD_FB()                                                  \
    {                                                                    \
        _Pragma("unroll")                                                \
        for (int k = 0; k < 3; ++k) {                                    \
            _Pragma("unroll")                                            \
            for (int e = 0; e < 2; ++e) {                                \
                float4 ld = make_float4(0.f, 0.f, 0.f, 0.f);             \
                if (okk[k]) ld = *(const float4*)&x2[o2k[k] + e * CHW];  \
                *(float4*)&pf[(k * 2 + e) * 4] = ld;                     \
            }                                                            \
            o2k[k] += KSTRIDE;                                           \
        }                                                                \
    }

#define X1_LOAD_FB()                                                     \
    {                                                                    \
        _Pragma("unroll")                                                \
        for (int j = 0; j < 8; ++j) pa[j] = x1[o1 + j * CHW];            \
        o1 += KSTRIDE;                                                   \
    }

    STAGE_LOAD_FB();
    X1_LOAD_FB();

    const int rbase = XBI(r, q, col);

    for (int ci = 0; ci < 8; ++ci) {
#pragma unroll
        for (int k = 0; k < 3; ++k) {
            if (act[k]) {
#pragma unroll
                for (int p = 0; p < 4; ++p) {
                    ushort2 v;
                    v.x = f2bf(pf[(k * 2 + 0) * 4 + p]);
                    v.y = f2bf(pf[(k * 2 + 1) * 4 + p]);
                    *(ushort2*)&lds.xb[lofk[k] + p * 8] = v;
                }
            }
        }
        __syncthreads();

        bf16x8 a;
#pragma unroll
        for (int j = 0; j < 8; ++j) a[j] = (short)f2bf(pa[j]);
        if (ci < 7) {
            STAGE_LOAD_FB();
            X1_LOAD_FB();
        }

#pragma unroll
        for (int s = 0; s < 9; ++s) {
            const int u    = dig * 9 + s;
            const int di   = u >> 1;
            const int half = u & 1;
            bf16x8 bb = *(const bf16x8*)&lds.xb[rbase + di * RS + half * 128];
            acc[s] = __builtin_amdgcn_mfma_f32_16x16x32_bf16(a, bb, acc[s], 0, 0, 0);
        }
        __syncthreads();
    }

#pragma unroll
    for (int s = 0; s < 9; ++s) {
        const int u  = dig * 9 + s;
        const int di = u >> 1;
        const int uh = u & 1;
#pragma unroll
        for (int rg = 0; rg < 4; ++rg) {
            int m  = q * 4 + rg;
            int dj = uh * 16 + col - m;
            if (dj >= 0 && dj < 9)
                lds.band[r][di][dj][m] = acc[s][rg];
        }
    }
    __syncthreads();

    const float scale = 1.0f / 256.0f;
#pragma unroll
    for (int it = 0; it < 11; ++it) {
        int gi = it * 32 + (tid >> 4);
        if (gi < 324) {
            int combo = gi >> 2;
            int row   = gi & 3;
            float v = lds.band[row][combo / 9][combo % 9][tid & 15];
            out[((size_t)((b * 81 + combo) * HH + h0 + row)) * WW + w0 + (tid & 15)] = v * scale;
        }
    }
}

extern "C" void kernel_launch(void* const* d_in, const int* in_sizes, int n_in,
                              void* d_out, int out_size, void* d_ws, size_t ws_size,
                              hipStream_t stream) {
    const float* x1 = (const float*)d_in[0];
    const float* x2 = (const float*)d_in[1];
    float* out = (float*)d_out;

    if (ws_size >= 2 * XT_BYTES) {
        unsigned short* xt1 = (unsigned short*)d_ws;
        unsigned short* xt2 = xt1 + XT_ELEMS;
        transpose_cast<<<dim3(9216), 256, 0, stream>>>(x1, x2, xt1, xt2);
        corr_mfma_bt<<<dim3(1152), 512, 0, stream>>>(xt1, xt2, out);
    } else {
        corr_mfma_fb<<<dim3(1152), 512, 0, stream>>>(x1, x2, out);
    }
}